// Round 8
// baseline (2646.979 us; speedup 1.0000x reference)
//
#include <hip/hip_runtime.h>
#include <math.h>

#define BATCH 32
#define SEQT 384
#define DIM 768
#define D3 2304
#define NROWS (BATCH*SEQT)      // 12288
#define VTHRESH 0.95f

typedef float  f32x4 __attribute__((ext_vector_type(4)));

// ---------------- workspace layout (bytes) ----------------
#define OFF_XP   ((size_t)0)
#define SZ_XP    ((size_t)NROWS * D3 * 4)            // 113,246,208
#define OFF_ST   (OFF_XP + SZ_XP)
#define SZ_ST    ((size_t)NROWS * DIM * 4)           // 37,748,736
#define OFF_PR   (OFF_ST + SZ_ST)
#define SZ_PR    ((size_t)NROWS * 4)
#define OFF_WT   (OFF_PR + SZ_PR)
#define OFF_SS   (OFF_WT + SZ_PR)
#define OFF_SE   (OFF_SS + SZ_PR)
#define OFF_NS   (OFF_SE + SZ_PR)
#define OFF_HB   (OFF_NS + 256)
// hbuf: 2 parity x 8 bg x 768 cols x 2 chunks x 16B = 393,216 B
// chunk layout per col: s0=[b0,b1,b2,tag]  s1=[b3,-,-,tag]
#define NBG 8               // batch groups (4 batches each)
#define BPG 4               // batches per group
#define WPB 32              // WGs per bg
#define CPW 24              // cols per WG
#define BGBYTES ((size_t)(DIM * 2 * 16))     // 24,576
#define SZ_HB   ((size_t)2 * NBG * BGBYTES)  // 393,216
#define INIT_FLOATS (SZ_HB/4)                // 98,304

#define DOT4(a,b) ((a).x*(b).x + (a).y*(b).y + (a).z*(b).z + (a).w*(b).w)

// fast transcendentals: v_exp_f32 / v_rcp_f32 (1 ulp — negligible vs
// the existing 2.4e-4 fp32-ordering absmax).
__device__ __forceinline__ float fexp2(float x) {
    float r; asm("v_exp_f32 %0, %1" : "=v"(r) : "v"(x)); return r;
}
__device__ __forceinline__ float frcp(float x) {
    float r; asm("v_rcp_f32 %0, %1" : "=v"(r) : "v"(x)); return r;
}
#define LOG2E 1.44269504f

// =========================================================
// K1: xp[m][n] = sum_k emb[sent[m]][k] * w_ih[n][k] + b_ih[n]
// =========================================================
__global__ __launch_bounds__(256, 2) void k_xp(
    const int* __restrict__ sent, const float* __restrict__ emb,
    const float* __restrict__ w_ih, const float* __restrict__ b_ih,
    float* __restrict__ xp)
{
    __shared__ float As[16][132];
    __shared__ float Bs[16][132];
    const int tid = threadIdx.x;
    const int mt = blockIdx.x, nt = blockIdx.y;
    const int tx = tid & 15, ty = tid >> 4;
    const int lm = tid >> 2;          // 0..63
    const int lk = (tid & 3) << 2;    // 0,4,8,12

    const long arow0 = (long)sent[mt*128 + lm] * DIM;
    const long arow1 = (long)sent[mt*128 + lm + 64] * DIM;
    const float* b0p = w_ih + (size_t)(nt*128 + lm) * DIM;
    const float* b1p = w_ih + (size_t)(nt*128 + lm + 64) * DIM;

    float acc[8][8];
    #pragma unroll
    for (int i = 0; i < 8; ++i)
        #pragma unroll
        for (int j = 0; j < 8; ++j) acc[i][j] = 0.f;

    for (int k0 = 0; k0 < DIM; k0 += 16) {
        float4 a0 = *(const float4*)(emb + arow0 + k0 + lk);
        float4 a1 = *(const float4*)(emb + arow1 + k0 + lk);
        float4 b0 = *(const float4*)(b0p + k0 + lk);
        float4 b1 = *(const float4*)(b1p + k0 + lk);
        __syncthreads();
        As[lk+0][lm] = a0.x; As[lk+1][lm] = a0.y; As[lk+2][lm] = a0.z; As[lk+3][lm] = a0.w;
        As[lk+0][lm+64] = a1.x; As[lk+1][lm+64] = a1.y; As[lk+2][lm+64] = a1.z; As[lk+3][lm+64] = a1.w;
        Bs[lk+0][lm] = b0.x; Bs[lk+1][lm] = b0.y; Bs[lk+2][lm] = b0.z; Bs[lk+3][lm] = b0.w;
        Bs[lk+0][lm+64] = b1.x; Bs[lk+1][lm+64] = b1.y; Bs[lk+2][lm+64] = b1.z; Bs[lk+3][lm+64] = b1.w;
        __syncthreads();
        #pragma unroll
        for (int k = 0; k < 16; ++k) {
            float4 av0 = *(const float4*)&As[k][ty*8];
            float4 av1 = *(const float4*)&As[k][ty*8+4];
            float4 bv0 = *(const float4*)&Bs[k][tx*8];
            float4 bv1 = *(const float4*)&Bs[k][tx*8+4];
            float a[8] = {av0.x,av0.y,av0.z,av0.w,av1.x,av1.y,av1.z,av1.w};
            float b[8] = {bv0.x,bv0.y,bv0.z,bv0.w,bv1.x,bv1.y,bv1.z,bv1.w};
            #pragma unroll
            for (int i = 0; i < 8; ++i)
                #pragma unroll
                for (int j = 0; j < 8; ++j)
                    acc[i][j] += a[i]*b[j];
        }
    }

    const int m0 = mt*128 + ty*8;
    const int n0 = nt*128 + tx*8;
    float4 bi0 = *(const float4*)(b_ih + n0);
    float4 bi1 = *(const float4*)(b_ih + n0 + 4);
    #pragma unroll
    for (int i = 0; i < 8; ++i) {
        float4 v0, v1;
        v0.x = acc[i][0] + bi0.x; v0.y = acc[i][1] + bi0.y;
        v0.z = acc[i][2] + bi0.z; v0.w = acc[i][3] + bi0.w;
        v1.x = acc[i][4] + bi1.x; v1.y = acc[i][5] + bi1.y;
        v1.z = acc[i][6] + bi1.z; v1.w = acc[i][7] + bi1.w;
        *(float4*)(xp + (size_t)(m0+i)*D3 + n0)     = v0;
        *(float4*)(xp + (size_t)(m0+i)*D3 + n0 + 4) = v1;
    }
}

// =========================================================
// K2: persistent GRU recurrence, v12 — XCD-affinity exchange.
//   R7 post-mortem: issue-trim landed (VALU-busy 1.13->0.96ms) but
//   exposed wait didn't move (~1.7us/step): every poll is sc0 sc1 =
//   MALL RT (~700-900cy), >=1 per step on the serial critical path.
//   v12: WGs round-robin across the 8 XCDs, so bg = blockIdx & 7 puts
//   ALL 32 WGs of a batch-group on ONE XCD. Producer publish stays
//   sc0 sc1 (write-through to MALL -> fallback correctness). Consumer
//   polls become sc0-only (bypass L1, hit LOCAL L2 that the
//   write-through just updated): RT ~200-300cy. Every 4th retry uses
//   sc0 sc1 (MALL) so a cross-XCD consumer still makes progress in
//   <=4 retries — correctness never depends on the XCD mapping,
//   only speed (per G16).
//   Everything else identical to v11 (split-k two-phase, fast gates,
//   asm-resident w4, tagged 1-RT protocol, 2-deep parity).
// =========================================================
#define HPITCH 772

__global__ __launch_bounds__(768, 1) void k_gru(
    const float* __restrict__ w_hh, const float* __restrict__ b_hh,
    const float* __restrict__ xp, float* __restrict__ states,
    char* __restrict__ hbuf)
{
    __shared__ float h_lds[2][BPG][HPITCH];   // 24,704 B

    const int tid = threadIdx.x;
    const int jb  = blockIdx.x >> 3;      // WG within bg (0..31)
    const int bg  = blockIdx.x & 7;       // XCD-affine batch-group
    const int w    = tid >> 6;            // wave 0..11
    const int lane = tid & 63;
    const int half = lane >> 5;           // which of the wave's 2 cols
    const int c32  = lane & 31;
    const int col  = jb*CPW + w*2 + half;
    const int bloc = (c32 >> 3) & 3;      // batch-in-group 0..3
    const int batch = bg*BPG + bloc;

    // weights: asm-opaque loads -> compiler cannot rematerialize.
    f32x4 w4[3][6];
    #pragma unroll
    for (int g3 = 0; g3 < 3; ++g3) {
        const float* wr = w_hh + (size_t)(g3*DIM + col)*DIM + c32*4;
        #pragma unroll
        for (int m = 0; m < 6; ++m) {
            const f32x4* ap = (const f32x4*)(wr + m*128);
            asm volatile("global_load_dwordx4 %0, %1, off"
                         : "=v"(w4[g3][m]) : "v"(ap));
        }
    }
    asm volatile("s_waitcnt vmcnt(0)" ::: "memory");
    __builtin_amdgcn_sched_barrier(0);

    const float bhr = b_hh[col];
    const float bhz = b_hh[DIM + col];
    const float bhn = b_hh[2*DIM + col];

    // consumer chunk assignment: i=0 -> lower half cols, i=1 -> upper
    int goff[2], ldsoff[2], onemask = 0;
    #pragma unroll
    for (int i = 0; i < 2; ++i) {
        int q = i*768 + tid;
        int cq = q >> 1, sq = q & 1;
        goff[i]   = q << 4;
        ldsoff[i] = (sq ? 3 : 0)*HPITCH + cq;
        if (sq) onemask |= (1<<i);      // s=1 carries only batch 3
    }

    char* pb[2];
    pb[0] = hbuf + (size_t)(0*NBG + bg)*BGBYTES;
    pb[1] = hbuf + (size_t)(1*NBG + bg)*BGBYTES;

    const float* xq = xp + (size_t)batch*SEQT*D3 + col;

    f32x4 ch[2];

// fast path: sc0-only (L1 bypass, local-L2 hit after write-through)
#define LOADCH_FAST(idx, pbx)                                            \
    {                                                                    \
        const f32x4* ap = (const f32x4*)((pbx) + goff[idx]);             \
        asm volatile("global_load_dwordx4 %0, %1, off sc0"               \
                     : "=v"(ch[idx]) : "v"(ap));                         \
    }
// fallback: sc0 sc1 (MALL) — guarantees progress if cross-XCD
#define LOADCH_SLOW(idx, pbx)                                            \
    {                                                                    \
        const f32x4* ap = (const f32x4*)((pbx) + goff[idx]);             \
        asm volatile("global_load_dwordx4 %0, %1, off sc0 sc1"           \
                     : "=v"(ch[idx]) : "v"(ap));                         \
    }

#define ISSUE_POLLS(pbx)                                                 \
    {                                                                    \
        LOADCH_FAST(0, pbx);                                             \
        LOADCH_FAST(1, pbx);                                             \
    }

#define GRU_GATES(xr, xz, xn, ar, az, an)                                \
    {                                                                    \
        float rg = frcp(1.f + fexp2(-LOG2E*((xr) + (ar) + bhr)));        \
        float zg = frcp(1.f + fexp2(-LOG2E*((xz) + (az) + bhz)));        \
        float sn = (xn) + rg * ((an) + bhn);                             \
        float ng = 1.f - 2.f*frcp(1.f + fexp2(2.f*LOG2E*sn));            \
        hold = (1.f - zg) * ng + zg * hold;                              \
    }

    // publish: lanes 0..3 build this wave's 2 cols x 2 subs.
#define PUBLISH(pbx, tt)                                                 \
    {                                                                    \
        int gp = (lane >> 1) & 1;                                        \
        int sq = lane & 1;                                               \
        float q0 = __shfl(hold, gp*32 + (sq ? 24 : 0));                  \
        float q1 = __shfl(hold, gp*32 + 8);                              \
        float q2 = __shfl(hold, gp*32 + 16);                             \
        if (lane < 4) {                                                  \
            f32x4 val;                                                   \
            val.x = q0; val.y = q1; val.z = q2;                          \
            val.w = __int_as_float((tt) + 1);                            \
            int colp = jb*CPW + w*2 + gp;                                \
            f32x4* ap = (f32x4*)((pbx) + (size_t)(colp*2 + sq)*16);      \
            asm volatile("global_store_dwordx4 %0, %1, off sc0 sc1"      \
                         :: "v"(ap), "v"(val) : "memory");               \
        }                                                                \
        if ((c32 & 7) == 0)                                              \
            states[(size_t)(batch*SEQT + (tt))*DIM + col] = hold;        \
    }

    float hold = 0.f;

    // ---------------- prologue: t = 0 (h = 0 -> recurrent accums 0)
    float xr = xq[0], xz = xq[DIM], xn = xq[2*DIM];
    GRU_GATES(xr, xz, xn, 0.f, 0.f, 0.f);
    PUBLISH(pb[0], 0);
    ISSUE_POLLS(pb[0]);                  // speculative sweep for t=1
    float xrn = xq[(size_t)D3], xzn = xq[(size_t)D3 + DIM],
          xnn = xq[(size_t)D3 + 2*DIM];

    // ---------------- main loop
    for (int t = 1; t < SEQT; ++t) {
        float* hb0 = &h_lds[t & 1][0][0];
        const char* pbx = pb[(t-1)&1];

        // ===== phase L: wait lower chunk; opportunistic upper =====
        asm volatile("s_waitcnt vmcnt(0)" ::: "memory");
        __builtin_amdgcn_sched_barrier(0);
        bool up_ok = (__float_as_int(ch[1].w) == t);
        {
            int spin = 0;
            while (__float_as_int(ch[0].w) != t) {
                __builtin_amdgcn_s_sleep(1);
                ++spin;
                if ((spin & 3) == 0) {          // periodic MALL fallback
                    LOADCH_SLOW(0, pbx);
                    if (!up_ok) LOADCH_SLOW(1, pbx);
                } else {                        // local-L2 fast path
                    LOADCH_FAST(0, pbx);
                    if (!up_ok) LOADCH_FAST(1, pbx);
                }
                asm volatile("s_waitcnt vmcnt(0)" ::: "memory");
                __builtin_amdgcn_sched_barrier(0);
                if (!up_ok) up_ok = (__float_as_int(ch[1].w) == t);
            }
        }
        // fill lower; upper now if valid, else launch one re-load
        hb0[ldsoff[0]] = ch[0].x;
        if (!(onemask & 1)) {
            hb0[ldsoff[0] + HPITCH]   = ch[0].y;
            hb0[ldsoff[0] + 2*HPITCH] = ch[0].z;
        }
        if (up_ok) {
            hb0[ldsoff[1]] = ch[1].x;
            if (!(onemask & 2)) {
                hb0[ldsoff[1] + HPITCH]   = ch[1].y;
                hb0[ldsoff[1] + 2*HPITCH] = ch[1].z;
            }
        } else {
            LOADCH_FAST(1, pbx);
        }
        xr = xrn; xz = xzn; xn = xnn;
        __syncthreads();                       // barrier A

        // ---- dots lower half: m = 0..2 (k in [0,384))
        float v[12];
        #pragma unroll
        for (int i = 0; i < 12; ++i) v[i] = 0.f;
        const float* hk = hb0 + c32*4;
        #pragma unroll
        for (int bb = 0; bb < 4; ++bb) {
            const float* hr = hk + bb*HPITCH;
            #pragma unroll
            for (int m = 0; m < 3; ++m) {
                f32x4 h4 = *(const f32x4*)(hr + m*128);
                v[bb*3+0] += DOT4(h4, w4[0][m]);
                v[bb*3+1] += DOT4(h4, w4[1][m]);
                v[bb*3+2] += DOT4(h4, w4[2][m]);
            }
        }

        // ===== phase U: validate + fill upper (usually pre-filled) =====
        if (!up_ok) {
            asm volatile("s_waitcnt vmcnt(0)" ::: "memory");
            __builtin_amdgcn_sched_barrier(0);
            int spin = 0;
            while (__float_as_int(ch[1].w) != t) {
                __builtin_amdgcn_s_sleep(1);
                ++spin;
                if ((spin & 3) == 0) { LOADCH_SLOW(1, pbx); }
                else                 { LOADCH_FAST(1, pbx); }
                asm volatile("s_waitcnt vmcnt(0)" ::: "memory");
                __builtin_amdgcn_sched_barrier(0);
            }
            hb0[ldsoff[1]] = ch[1].x;
            if (!(onemask & 2)) {
                hb0[ldsoff[1] + HPITCH]   = ch[1].y;
                hb0[ldsoff[1] + 2*HPITCH] = ch[1].z;
            }
        }
        __syncthreads();                       // barrier B

        // xp(t+1) prefetch: flies across upper dots + publish
        if (t + 1 < SEQT) {
            xrn = xq[(size_t)(t+1)*D3];
            xzn = xq[(size_t)(t+1)*D3 + DIM];
            xnn = xq[(size_t)(t+1)*D3 + 2*DIM];
        }

        // ---- dots upper half: m = 3..5 (k in [384,768))
        #pragma unroll
        for (int bb = 0; bb < 4; ++bb) {
            const float* hr = hk + bb*HPITCH;
            #pragma unroll
            for (int m = 3; m < 6; ++m) {
                f32x4 h4 = *(const f32x4*)(hr + m*128);
                v[bb*3+0] += DOT4(h4, w4[0][m]);
                v[bb*3+1] += DOT4(h4, w4[1][m]);
                v[bb*3+2] += DOT4(h4, w4[2][m]);
            }
        }
        // ---- reduce: bits 4,3 -> batch (scatter), 2,1,0 butterfly
        #pragma unroll
        for (int i = 0; i < 6; ++i) {
            float send = (c32 & 16) ? v[i] : v[i+6];
            float keep = (c32 & 16) ? v[i+6] : v[i];
            v[i] = keep + __shfl_xor(send, 16);
        }
        #pragma unroll
        for (int i = 0; i < 3; ++i) {
            float send = (c32 & 8) ? v[i] : v[i+3];
            float keep = (c32 & 8) ? v[i+3] : v[i];
            v[i] = keep + __shfl_xor(send, 8);
        }
        #pragma unroll
        for (int i = 0; i < 3; ++i) v[i] += __shfl_xor(v[i], 4);
        #pragma unroll
        for (int i = 0; i < 3; ++i) v[i] += __shfl_xor(v[i], 2);
        #pragma unroll
        for (int i = 0; i < 3; ++i) v[i] += __shfl_xor(v[i], 1);

        GRU_GATES(xr, xz, xn, v[0], v[1], v[2]);
        PUBLISH(pb[t&1], t);
        if (t + 1 < SEQT)
            ISSUE_POLLS(pb[t&1]);        // speculative sweep for t+1
    }
#undef ISSUE_POLLS
#undef LOADCH_FAST
#undef LOADCH_SLOW
#undef GRU_GATES
#undef PUBLISH
}

// =========================================================
// K3: probs[r] = sigmoid(dot(states[r], w_act) + b_act)
// =========================================================
__global__ __launch_bounds__(256, 4) void k_probs(
    const float* __restrict__ states, const float* __restrict__ w_act,
    const float* __restrict__ b_act, float* __restrict__ probs,
    float* __restrict__ out_probs)
{
    int row  = blockIdx.x*4 + (threadIdx.x >> 6);
    int lane = threadIdx.x & 63;
    const float* sr = states + (size_t)row * DIM;
    float s = 0.f;
    #pragma unroll
    for (int i = 0; i < 3; ++i) {
        float4 v = *(const float4*)(sr + i*256 + lane*4);
        float4 w = *(const float4*)(w_act + i*256 + lane*4);
        s += v.x*w.x + v.y*w.y + v.z*w.z + v.w*w.w;
    }
    #pragma unroll
    for (int off = 32; off > 0; off >>= 1) s += __shfl_xor(s, off);
    if (lane == 0) {
        float pv = 1.f / (1.f + expf(-(s + b_act[0])));
        probs[row]     = pv;
        out_probs[row] = pv;
    }
}

// =========================================================
// K4: per-batch halting scan -> weights, segment bounds, n_segs
// =========================================================
__global__ void k_scan(const float* __restrict__ probs, float* __restrict__ weights,
                       int* __restrict__ seg_start, int* __restrict__ seg_end,
                       int* __restrict__ n_segs)
{
    int b = threadIdx.x;
    if (b >= BATCH) return;
    float acc = 0.f;
    int s = 0, start = 0;
    for (int t0 = 0; t0 < SEQT; t0 += 4) {
        float4 p4 = *(const float4*)(probs + b*SEQT + t0);
        float pv[4] = {p4.x, p4.y, p4.z, p4.w};
        #pragma unroll
        for (int k = 0; k < 4; ++k) {
            int t = t0 + k;
            float pp = pv[k];
            acc += pp;
            float w = pp;
            if (acc > VTHRESH) {
                w = pp - (acc - 1.0f);
                seg_start[b*SEQT + s] = start;
                seg_end[b*SEQT + s]   = t;
                s++; start = t + 1; acc = 0.f;
            }
            weights[b*SEQT + t] = w;
        }
    }
    n_segs[b] = s;
}

// =========================================================
// K5: embs row (b,s) = sum_{t in segment s} weights[b,t]*states[b,t,:]
// =========================================================
__global__ __launch_bounds__(256, 4) void k_embs(
    const float* __restrict__ states, const float* __restrict__ weights,
    const int* __restrict__ seg_start, const int* __restrict__ seg_end,
    const int* __restrict__ n_segs, float* __restrict__ out)
{
    int r = blockIdx.x;
    int b = r / SEQT;
    int s = r - b*SEQT;
    int tid = threadIdx.x;
    float a0 = 0.f, a1 = 0.f, a2 = 0.f;
    if (s < n_segs[b]) {
        int st = seg_start[r], en = seg_end[r];
        for (int t = st; t <= en; ++t) {
            float w = weights[b*SEQT + t];
            const float* sp = states + (size_t)(b*SEQT + t) * DIM;
            a0 += w * sp[tid];
            a1 += w * sp[tid + 256];
            a2 += w * sp[tid + 512];
        }
    }
    float* o = out + (size_t)r * DIM;
    o[tid]       = a0;
    o[tid + 256] = a1;
    o[tid + 512] = a2;
}

__global__ void k_init(float* hb) {
    int i = blockIdx.x * 256 + threadIdx.x;
    if (i < INIT_FLOATS) hb[i] = 0.f;
}

extern "C" void kernel_launch(void* const* d_in, const int* in_sizes, int n_in,
                              void* d_out, int out_size, void* d_ws, size_t ws_size,
                              hipStream_t stream)
{
    const int*   sent  = (const int*)d_in[0];
    const float* emb   = (const float*)d_in[1];
    const float* w_ih  = (const float*)d_in[2];
    const float* w_hh  = (const float*)d_in[3];
    const float* b_ih  = (const float*)d_in[4];
    const float* b_hh  = (const float*)d_in[5];
    const float* w_act = (const float*)d_in[6];
    const float* b_act = (const float*)d_in[7];
    float* out = (float*)d_out;

    char* ws = (char*)d_ws;
    float* xp      = (float*)(ws + OFF_XP);
    float* states  = (float*)(ws + OFF_ST);
    float* probs   = (float*)(ws + OFF_PR);
    float* weights = (float*)(ws + OFF_WT);
    int*   sstart  = (int*)(ws + OFF_SS);
    int*   send    = (int*)(ws + OFF_SE);
    int*   nsegs   = (int*)(ws + OFF_NS);
    char*  hbuf    = (char*)(ws + OFF_HB);

    k_init<<<384, 256, 0, stream>>>((float*)hbuf);
    k_xp<<<dim3(96, 18), 256, 0, stream>>>(sent, emb, w_ih, b_ih, xp);
    k_gru<<<256, 768, 0, stream>>>(w_hh, b_hh, xp, states, hbuf);
    k_probs<<<NROWS/4, 256, 0, stream>>>(states, w_act, b_act, probs,
                                         out + (size_t)NROWS * DIM);
    k_scan<<<1, 64, 0, stream>>>(probs, weights, sstart, send, nsegs);
    k_embs<<<NROWS, 256, 0, stream>>>(states, weights, sstart, send, nsegs, out);
}